// Round 17
// baseline (352.084 us; speedup 1.0000x reference)
//
#include <hip/hip_runtime.h>
#include <math.h>

// DN test-mode forward, filter+rescore.
// gemm: BM=512 (full M) x BN=128, 256 blocks = 1/CU, W read ONCE (512MB, NT).
// R15 structure + W staged in 64-col SUPER-tiles: 256B contiguous per row per
// fetch (vs 128B) -> better DRAM row-buffer locality. Ring-4 K-tile LDS bufs,
// barrier cadence unchanged (1/K-tile). Read side identical to R15.

typedef _Float16 half8 __attribute__((ext_vector_type(8)));
typedef __attribute__((ext_vector_type(16))) float f32x16;
typedef float f32x4 __attribute__((ext_vector_type(4)));
typedef unsigned long long ull;

#define TAU 0.006f
#define CAP 1572864u
#define LCAP 1536u

__device__ __forceinline__ unsigned pk2h(float a, float b) {
    union { _Float16 h; unsigned short u; } ca, cb;
    ca.h = (_Float16)a; cb.h = (_Float16)b;   // RNE
    return (unsigned)ca.u | ((unsigned)cb.u << 16);
}

// monotone-float key, smaller y wins ties
__device__ __forceinline__ ull packkey(float v, unsigned y) {
    unsigned m = __float_as_uint(v);
    m = (v >= 0.f) ? (m | 0x80000000u) : ~m;
    return ((ull)m << 32) | (ull)(0x7FFFFFFFu - y);
}

__global__ __launch_bounds__(512) void init_ctrl(const int* __restrict__ age,
                                                 ull* __restrict__ win,
                                                 unsigned* __restrict__ cnt) {
    const int t = threadIdx.x;
    int fi = 0x7fffffff;
    for (int y = t; y < 32768; y += 512)
        if (age[y] < 1) fi = min(fi, y);
    __shared__ int red[512];
    red[t] = fi;
    __syncthreads();
    for (int s = 256; s; s >>= 1) {
        if (t < s) red[t] = min(red[t], red[t + s]);
        __syncthreads();
    }
    const int f = red[0];
    const ull seed = (f < 32768) ? packkey(0.0f, (unsigned)f) : packkey(-1e30f, 0u);
    win[t] = seed;                      // t < 512 = B
    if (t == 0) *cnt = 0u;
}

// x -> f16 fragments: o = (t<<11)|(wm<<8)|(mi<<7)|(ks<<6)|lane
__global__ __launch_bounds__(512) void convert_x(const float* __restrict__ x,
                                                 uint4* __restrict__ xf16) {
    const int o = blockIdx.x * 512 + threadIdx.x;   // 262144
    const int lane = o & 63;
    const int ks = (o >> 6) & 1;
    const int mi = (o >> 7) & 1;
    const int wm = (o >> 8) & 7;
    const int t  = o >> 11;
    const int row = (wm << 6) + (mi << 5) + (lane & 31);
    const int col = (t << 5) + (ks << 4) + ((lane >> 5) << 3);
    const float* src = x + (size_t)row * 4096 + col;
    const float4 a = *(const float4*)src;
    const float4 b = *(const float4*)(src + 4);
    uint4 u;
    u.x = pk2h(a.x, a.y); u.y = pk2h(a.z, a.w);
    u.z = pk2h(b.x, b.y); u.w = pk2h(b.z, b.w);
    xf16[o] = u;
}

__global__ __launch_bounds__(256) void row_norms(const float* __restrict__ src,
                                                 float* __restrict__ dst, int cols) {
    const int r = blockIdx.x;
    const float* row = src + (size_t)r * cols;
    const int t = threadIdx.x;
    float s = 0.f;
    const int nIter = cols >> 10;
    for (int i = 0; i < nIter; ++i) {
        const float4 v = *reinterpret_cast<const float4*>(row + (((i << 8) + t) << 2));
        s = fmaf(v.x, v.x, s); s = fmaf(v.y, v.y, s);
        s = fmaf(v.z, v.z, s); s = fmaf(v.w, v.w, s);
    }
    #pragma unroll
    for (int off = 32; off; off >>= 1) s += __shfl_down(s, off);
    __shared__ float red[4];
    if ((t & 63) == 0) red[t >> 6] = s;
    __syncthreads();
    if (t == 0) dst[r] = sqrtf(red[0] + red[1] + red[2] + red[3]);
}

__global__ __launch_bounds__(512, 2) void gemm_f16(
    const float* __restrict__ w,      // [32768][4096]
    const uint4* __restrict__ xf16,   // pre-converted x fragments
    const int*  __restrict__ age,
    float* __restrict__ cand,         // [512][256] block-row approx max
    float2* __restrict__ ent,         // candidate list
    unsigned* __restrict__ cnt)
{
    __shared__ uint4 Bl[4][512];      // ring-4 K-tile bufs (swizzled slots)
    __shared__ float ny_inv[128];
    __shared__ float rowmaxs[512];
    __shared__ float2 lent[LCAP];
    __shared__ unsigned lcnt, gbase;

    const int tid = threadIdx.x;
    const int y0 = blockIdx.x << 7;   // 256 blocks = y-chunks

    // W staging: 4 threads/row, 16 f32 (64B) each per SUPER (64 cols);
    // 4 lanes = 256B contiguous segment.
    const int rB = tid >> 2, q = tid & 3;
    const int sb = (q & 1) << 1;      // slot base within target K-tile
    const int wi0 = (rB << 2) + ((sb    ) ^ (rB & 3));
    const int wi1 = (rB << 2) + ((sb | 1) ^ (rB & 3));
    const float* bP = w + (size_t)(y0 + rB) * 4096 + (q << 4);

    // 8 waves = 8 x wm; wave tile 64M x 128N; 32x32x16 f16 frags
    const int lane = tid & 63, wm = tid >> 6;
    const int kh = lane >> 5, cc = lane & 3;
    const uint4* aP = xf16 + (wm << 8) + lane;

    const int rb0 = ((lane & 31)      ) << 2;
    const int rb1 = ((lane & 31) +  32) << 2;
    const int rb2 = ((lane & 31) +  64) << 2;
    const int rb3 = ((lane & 31) +  96) << 2;
    const int s0 = kh ^ cc, s1 = (2 | kh) ^ cc;

    f32x16 am0n0 = (f32x16)0.f, am0n1 = (f32x16)0.f;
    f32x16 am0n2 = (f32x16)0.f, am0n3 = (f32x16)0.f;
    f32x16 am1n0 = (f32x16)0.f, am1n1 = (f32x16)0.f;
    f32x16 am1n2 = (f32x16)0.f, am1n3 = (f32x16)0.f;

    half8 pa00, pa01, pa10, pa11;     // A set P (mi,ks)
    half8 qa00, qa01, qa10, qa11;     // A set Q
    half8 g00, g10, g20, g30;         // B frags ks0 (ni 0..3)
    half8 g01, g11, g21, g31;         // B frags ks1
    f32x4 SAa, SAb, SAc, SAd;         // W set A (even supers) - nt-loaded
    f32x4 SBa, SBb, SBc, SBd;         // W set B (odd supers)
    float nyacc = 0.f;

#define MF(a, b, c) __builtin_amdgcn_mfma_f32_32x32x16_f16(a, b, c, 0, 0, 0)
#define LG0 asm volatile("s_waitcnt lgkmcnt(0)" ::: "memory")
#define SBR __builtin_amdgcn_sched_barrier(0)
#define BAR __builtin_amdgcn_s_barrier()

#define LOADA(S, tt) { const uint4* p_ = aP + ((size_t)(tt) << 11); \
    S##00 = *(const half8*)(p_);        S##01 = *(const half8*)(p_ + 64); \
    S##10 = *(const half8*)(p_ + 128);  S##11 = *(const half8*)(p_ + 192); }

// NON-TEMPORAL 64B/thread: super st covers f32 cols [st*64, st*64+64)
#define LOADW(S, st) { const f32x4* p_ = (const f32x4*)(bP + ((st) << 6)); \
    S##a = __builtin_nontemporal_load(p_); \
    S##b = __builtin_nontemporal_load(p_ + 1); \
    S##c = __builtin_nontemporal_load(p_ + 2); \
    S##d = __builtin_nontemporal_load(p_ + 3); }

// Write BOTH K-tiles of a super: q<2 -> even tile buf, q>=2 -> odd tile buf
#define STOREB2(bufE, bufO, S) { uint4 u0_, u1_; \
    u0_.x = pk2h(S##a.x, S##a.y); u0_.y = pk2h(S##a.z, S##a.w); \
    u0_.z = pk2h(S##b.x, S##b.y); u0_.w = pk2h(S##b.z, S##b.w); \
    u1_.x = pk2h(S##c.x, S##c.y); u1_.y = pk2h(S##c.z, S##c.w); \
    u1_.z = pk2h(S##d.x, S##d.y); u1_.w = pk2h(S##d.z, S##d.w); \
    uint4* dst_ = (q < 2) ? Bl[bufE] : Bl[bufO]; \
    dst_[wi0] = u0_; dst_[wi1] = u1_; \
    nyacc = fmaf(S##a.x, S##a.x, nyacc); nyacc = fmaf(S##a.y, S##a.y, nyacc); \
    nyacc = fmaf(S##a.z, S##a.z, nyacc); nyacc = fmaf(S##a.w, S##a.w, nyacc); \
    nyacc = fmaf(S##b.x, S##b.x, nyacc); nyacc = fmaf(S##b.y, S##b.y, nyacc); \
    nyacc = fmaf(S##b.z, S##b.z, nyacc); nyacc = fmaf(S##b.w, S##b.w, nyacc); \
    nyacc = fmaf(S##c.x, S##c.x, nyacc); nyacc = fmaf(S##c.y, S##c.y, nyacc); \
    nyacc = fmaf(S##c.z, S##c.z, nyacc); nyacc = fmaf(S##c.w, S##c.w, nyacc); \
    nyacc = fmaf(S##d.x, S##d.x, nyacc); nyacc = fmaf(S##d.y, S##d.y, nyacc); \
    nyacc = fmaf(S##d.z, S##d.z, nyacc); nyacc = fmaf(S##d.w, S##d.w, nyacc); }

#define LDB(cur) { \
    g00 = *(const half8*)&Bl[cur][rb0 + s0]; g01 = *(const half8*)&Bl[cur][rb0 + s1]; \
    g10 = *(const half8*)&Bl[cur][rb1 + s0]; g11 = *(const half8*)&Bl[cur][rb1 + s1]; \
    g20 = *(const half8*)&Bl[cur][rb2 + s0]; g21 = *(const half8*)&Bl[cur][rb2 + s1]; \
    g30 = *(const half8*)&Bl[cur][rb3 + s0]; g31 = *(const half8*)&Bl[cur][rb3 + s1]; }

#define MFMA16(S) { \
    am0n0 = MF(S##00, g00, am0n0); am0n1 = MF(S##00, g10, am0n1); \
    am0n2 = MF(S##00, g20, am0n2); am0n3 = MF(S##00, g30, am0n3); \
    am1n0 = MF(S##10, g00, am1n0); am1n1 = MF(S##10, g10, am1n1); \
    am1n2 = MF(S##10, g20, am1n2); am1n3 = MF(S##10, g30, am1n3); \
    am0n0 = MF(S##01, g01, am0n0); am0n1 = MF(S##01, g11, am0n1); \
    am0n2 = MF(S##01, g21, am0n2); am0n3 = MF(S##01, g31, am0n3); \
    am1n0 = MF(S##11, g01, am1n0); am1n1 = MF(S##11, g11, am1n1); \
    am1n2 = MF(S##11, g21, am1n2); am1n3 = MF(S##11, g31, am1n3); }

    // ---- prologue: super0 -> bufs 0,1; SB <- super1; SA <- super2 ----
    LOADW(SA, 0);
    LOADA(pa, 0);
    STOREB2(0, 1, SA);                // compiler waits SA
    LOADW(SB, 1);
    LOADW(SA, 2);
    LG0; SBR; BAR;

    // Ring-4: period t reads buf t&3; even periods of super s write bufs of
    // super s+1 (disjoint); one raw barrier per K-tile (cadence = R15).
    for (int s = 0; s < 64; s += 2) {
        const int t0 = s << 1;
        // t0: read buf0; store super s+1 (SB) -> bufs 2,3; load SB <- super s+3
        LDB(0); LOADA(qa, t0 + 1);
        STOREB2(2, 3, SB);
        if (s + 3 < 64) LOADW(SB, s + 3);
        MFMA16(pa); LG0; SBR; BAR;
        // t0+1: read buf1
        LDB(1); LOADA(pa, t0 + 2);
        MFMA16(qa); LG0; SBR; BAR;
        // t0+2: read buf2; store super s+2 (SA) -> bufs 0,1; load SA <- s+4
        LDB(2); LOADA(qa, t0 + 3);
        if (s + 2 < 64) STOREB2(0, 1, SA);
        if (s + 4 < 64) LOADW(SA, s + 4);
        MFMA16(pa); LG0; SBR; BAR;
        // t0+3: read buf3
        LDB(3); if (t0 + 4 < 128) LOADA(pa, t0 + 4);
        MFMA16(qa); LG0; SBR; BAR;
    }

    // ---- fused ||w_y|| (4 threads/row) ----
    float s_ = nyacc;
    s_ += __shfl_xor(s_, 1);
    s_ += __shfl_xor(s_, 2);
    if (q == 0) ny_inv[rB] = 1.0f / fmaxf(sqrtf(s_), 1e-12f);
    if (tid == 0) lcnt = 0u;
    __syncthreads();

    // ---- epilogue ----
    // am{mi}n{ni}[v] = S[wm*64+mi*32+(v&3)+8*(v>>2)+4*kh][y0+ni*32+(lane&31)]
    const int yl0 = (lane & 31), yl1 = yl0 + 32, yl2 = yl0 + 64, yl3 = yl0 + 96;
    const float scl0 = ny_inv[yl0], scl1 = ny_inv[yl1];
    const float scl2 = ny_inv[yl2], scl3 = ny_inv[yl3];
    const int act0 = age[y0 + yl0] >= 1, act1 = age[y0 + yl1] >= 1;
    const int act2 = age[y0 + yl2] >= 1, act3 = age[y0 + yl3] >= 1;
    const int yb0 = y0 + yl0, yb1 = y0 + yl1, yb2 = y0 + yl2, yb3 = y0 + yl3;
    const int rbase = (wm << 6) + (kh << 2);

#define ROWMAX(A0, A1, A2, A3, mi5) \
    _Pragma("unroll") for (int v = 0; v < 16; ++v) { \
        float bv = fmaxf( \
            fmaxf(act0 ? A0[v] * scl0 : 0.f, act1 ? A1[v] * scl1 : 0.f), \
            fmaxf(act2 ? A2[v] * scl2 : 0.f, act3 ? A3[v] * scl3 : 0.f)); \
        _Pragma("unroll") for (int off = 1; off < 32; off <<= 1) \
            bv = fmaxf(bv, __shfl_xor(bv, off)); \
        if ((lane & 31) == 0) \
            rowmaxs[rbase + (mi5) + (v & 3) + ((v >> 2) << 3)] = bv; \
    }
    ROWMAX(am0n0, am0n1, am0n2, am0n3, 0)
    ROWMAX(am1n0, am1n1, am1n2, am1n3, 32)
    __syncthreads();
    cand[(size_t)tid * 256 + blockIdx.x] = rowmaxs[tid];   // 512 rows
    __syncthreads();

#define APP1(ACv, actk, sclk, ybk, r_) { \
    if (actk) { const float sc_ = (ACv) * sclk; \
        if (sc_ >= rowmaxs[r_] - TAU) { \
            const unsigned ix_ = atomicAdd(&lcnt, 1u); \
            if (ix_ < LCAP) lent[ix_] = make_float2(sc_, \
                __uint_as_float(((unsigned)(r_) << 16) | (unsigned)(ybk))); } } }

#define APPEND(A0, A1, A2, A3, mi5) \
    _Pragma("unroll") for (int v = 0; v < 16; ++v) { \
        const int r_ = rbase + (mi5) + (v & 3) + ((v >> 2) << 3); \
        APP1(A0[v], act0, scl0, yb0, r_) \
        APP1(A1[v], act1, scl1, yb1, r_) \
        APP1(A2[v], act2, scl2, yb2, r_) \
        APP1(A3[v], act3, scl3, yb3, r_) }
    APPEND(am0n0, am0n1, am0n2, am0n3, 0)
    APPEND(am1n0, am1n1, am1n2, am1n3, 32)
    __syncthreads();
    if (tid == 0) gbase = atomicAdd(cnt, min(lcnt, LCAP));
    __syncthreads();
    const unsigned nL = min(lcnt, LCAP);
    for (unsigned i = tid; i < nL; i += 512) {
        const unsigned gi = gbase + i;
        if (gi < CAP) ent[gi] = lent[i];
    }
#undef MF
#undef LG0
#undef SBR
#undef BAR
#undef LOADA
#undef LOADW
#undef STOREB2
#undef LDB
#undef MFMA16
#undef ROWMAX
#undef APP1
#undef APPEND
}

__global__ __launch_bounds__(256) void reduce_gmax(const float* __restrict__ cand,
                                                   float* __restrict__ gmax) {
    const int b = blockIdx.x, t = threadIdx.x;
    float m = cand[(size_t)b * 256 + t];
    #pragma unroll
    for (int off = 32; off; off >>= 1) m = fmaxf(m, __shfl_xor(m, off));
    __shared__ float sm[4];
    if ((t & 63) == 0) sm[t >> 6] = m;
    __syncthreads();
    if (t == 0) gmax[b] = fmaxf(fmaxf(sm[0], sm[1]), fmaxf(sm[2], sm[3]));
}

// exact f32 rescore; ballot-compacted scan, wave-per-survivor dot product
__global__ __launch_bounds__(256) void rescore(
    const float* __restrict__ x, const float* __restrict__ w,
    const float* __restrict__ gmax, const float2* __restrict__ ent,
    const unsigned* __restrict__ cnt, ull* __restrict__ win)
{
    const unsigned n = min(*cnt, CAP);
    const int lane = threadIdx.x & 63;
    const unsigned wid = (blockIdx.x * 256 + threadIdx.x) >> 6;
    const unsigned nwv = (gridDim.x * 256) >> 6;
    for (unsigned base = wid << 6; base < n; base += (nwv << 6)) {
        const unsigned e = base + (unsigned)lane;
        unsigned by = 0u;
        bool ok = false;
        if (e < n) {
            const float2 en = ent[e];
            by = __float_as_uint(en.y);
            ok = en.x >= gmax[by >> 16] - TAU;
        }
        ull m = __ballot(ok);
        while (m) {
            const int s = __ffsll((ull)m) - 1;
            m &= m - 1;
            const unsigned bys = __shfl(by, s);
            const unsigned b = bys >> 16, y = bys & 0xffffu;
            const float4* xr = (const float4*)(x + (size_t)b * 4096);
            const float4* wr = (const float4*)(w + (size_t)y * 4096);
            float sdot = 0.f, nn = 0.f;
            #pragma unroll
            for (int k = 0; k < 16; ++k) {
                const float4 xv = xr[(k << 6) + lane];
                const float4 wv = wr[(k << 6) + lane];
                sdot = fmaf(xv.x, wv.x, sdot); sdot = fmaf(xv.y, wv.y, sdot);
                sdot = fmaf(xv.z, wv.z, sdot); sdot = fmaf(xv.w, wv.w, sdot);
                nn = fmaf(wv.x, wv.x, nn); nn = fmaf(wv.y, wv.y, nn);
                nn = fmaf(wv.z, wv.z, nn); nn = fmaf(wv.w, wv.w, nn);
            }
            #pragma unroll
            for (int off = 32; off; off >>= 1) {
                sdot += __shfl_xor(sdot, off);
                nn   += __shfl_xor(nn, off);
            }
            if (lane == 0) {
                const float sc = sdot / fmaxf(sqrtf(nn), 1e-12f);
                atomicMax(win + b, packkey(sc, y));
            }
        }
    }
}

__global__ __launch_bounds__(256) void gather_out(const float* __restrict__ y2z,
                                                  const float* __restrict__ nz,
                                                  const ull* __restrict__ win,
                                                  float* __restrict__ out) {
    const int g = blockIdx.x * 256 + threadIdx.x;
    if (g >= 512 * 1000) return;
    const int b = g / 1000, z = g - b * 1000;
    const unsigned lo = (unsigned)(win[b] & 0xffffffffull);
    const int yw = (int)(0x7FFFFFFFu - lo);
    out[g] = y2z[(size_t)z * 32768 + yw] / fmaxf(nz[z], 1e-12f);
}

extern "C" void kernel_launch(void* const* d_in, const int* in_sizes, int n_in,
                              void* d_out, int out_size, void* d_ws, size_t ws_size,
                              hipStream_t stream) {
    const float* x     = (const float*)d_in[0];
    const float* x2y_w = (const float*)d_in[2];
    const float* y2z_w = (const float*)d_in[3];
    const int*   y_age = (const int*)d_in[4];
    float* out = (float*)d_out;

    // ws layout (bytes)
    char* p = (char*)d_ws;
    float*    cand = (float*)p;                       // 512*256*4 = 524288
    float*    nz   = (float*)(p + 524288);            // 4096
    float*    gmax = (float*)(p + 528384);            // 2048
    ull*      win  = (ull*)(p + 530432);              // 4096
    unsigned* cnt  = (unsigned*)(p + 534528);         // 64
    uint4*    xf16 = (uint4*)(p + 534592);            // 4 MB
    float2*   ent  = (float2*)(p + 4728896);          // CAP*8

    init_ctrl<<<1, 512, 0, stream>>>(y_age, win, cnt);
    convert_x<<<512, 512, 0, stream>>>(x, xf16);
    row_norms<<<1000, 256, 0, stream>>>(y2z_w, nz, 32768);

    gemm_f16<<<256, 512, 0, stream>>>(x2y_w, xf16, y_age, cand, ent, cnt);
    reduce_gmax<<<512, 256, 0, stream>>>(cand, gmax);
    rescore<<<256, 256, 0, stream>>>(x, x2y_w, gmax, ent, cnt, win);
    gather_out<<<(512 * 1000 + 255) / 256, 256, 0, stream>>>(y2z_w, nz, win, out);
}

// Round 18
// 294.745 us; speedup vs baseline: 1.1945x; 1.1945x over previous
//
#include <hip/hip_runtime.h>
#include <math.h>

// DN test-mode forward, filter+rescore.
// gemm: BM=512 (full M) x BN=64, grid 512 = TWO blocks/CU (m97/m114 overlap:
// co-resident block fills the other's barrier/latency bubbles). W read ONCE
// (512MB, NT). VGPR engineered <=128 for 2-block residency: accs 64, single
// A-set, staging confined to waves 0-3. Pipeline = R15 (raw barrier + lgkm0,
// no vmcnt drains, 2-tile W cover, same swizzle/epilogue/filter/rescore).

typedef _Float16 half8 __attribute__((ext_vector_type(8)));
typedef __attribute__((ext_vector_type(16))) float f32x16;
typedef float f32x4 __attribute__((ext_vector_type(4)));
typedef unsigned long long ull;

#define TAU 0.006f
#define CAP 1572864u
#define LCAP 1024u

__device__ __forceinline__ unsigned pk2h(float a, float b) {
    union { _Float16 h; unsigned short u; } ca, cb;
    ca.h = (_Float16)a; cb.h = (_Float16)b;   // RNE
    return (unsigned)ca.u | ((unsigned)cb.u << 16);
}

// monotone-float key, smaller y wins ties
__device__ __forceinline__ ull packkey(float v, unsigned y) {
    unsigned m = __float_as_uint(v);
    m = (v >= 0.f) ? (m | 0x80000000u) : ~m;
    return ((ull)m << 32) | (ull)(0x7FFFFFFFu - y);
}

__global__ __launch_bounds__(512) void init_ctrl(const int* __restrict__ age,
                                                 ull* __restrict__ win,
                                                 unsigned* __restrict__ cnt) {
    const int t = threadIdx.x;
    int fi = 0x7fffffff;
    for (int y = t; y < 32768; y += 512)
        if (age[y] < 1) fi = min(fi, y);
    __shared__ int red[512];
    red[t] = fi;
    __syncthreads();
    for (int s = 256; s; s >>= 1) {
        if (t < s) red[t] = min(red[t], red[t + s]);
        __syncthreads();
    }
    const int f = red[0];
    const ull seed = (f < 32768) ? packkey(0.0f, (unsigned)f) : packkey(-1e30f, 0u);
    win[t] = seed;                      // t < 512 = B
    if (t == 0) *cnt = 0u;
}

// x -> f16 fragments: o = (t<<11)|(wm<<8)|(mi<<7)|(ks<<6)|lane
__global__ __launch_bounds__(512) void convert_x(const float* __restrict__ x,
                                                 uint4* __restrict__ xf16) {
    const int o = blockIdx.x * 512 + threadIdx.x;   // 262144
    const int lane = o & 63;
    const int ks = (o >> 6) & 1;
    const int mi = (o >> 7) & 1;
    const int wm = (o >> 8) & 7;
    const int t  = o >> 11;
    const int row = (wm << 6) + (mi << 5) + (lane & 31);
    const int col = (t << 5) + (ks << 4) + ((lane >> 5) << 3);
    const float* src = x + (size_t)row * 4096 + col;
    const float4 a = *(const float4*)src;
    const float4 b = *(const float4*)(src + 4);
    uint4 u;
    u.x = pk2h(a.x, a.y); u.y = pk2h(a.z, a.w);
    u.z = pk2h(b.x, b.y); u.w = pk2h(b.z, b.w);
    xf16[o] = u;
}

__global__ __launch_bounds__(256) void row_norms(const float* __restrict__ src,
                                                 float* __restrict__ dst, int cols) {
    const int r = blockIdx.x;
    const float* row = src + (size_t)r * cols;
    const int t = threadIdx.x;
    float s = 0.f;
    const int nIter = cols >> 10;
    for (int i = 0; i < nIter; ++i) {
        const float4 v = *reinterpret_cast<const float4*>(row + (((i << 8) + t) << 2));
        s = fmaf(v.x, v.x, s); s = fmaf(v.y, v.y, s);
        s = fmaf(v.z, v.z, s); s = fmaf(v.w, v.w, s);
    }
    #pragma unroll
    for (int off = 32; off; off >>= 1) s += __shfl_down(s, off);
    __shared__ float red[4];
    if ((t & 63) == 0) red[t >> 6] = s;
    __syncthreads();
    if (t == 0) dst[r] = sqrtf(red[0] + red[1] + red[2] + red[3]);
}

__global__ __launch_bounds__(512, 4) void gemm_f16(
    const float* __restrict__ w,      // [32768][4096]
    const uint4* __restrict__ xf16,   // pre-converted x fragments
    const int*  __restrict__ age,
    float* __restrict__ cand,         // [512][512] block-row approx max
    float2* __restrict__ ent,         // candidate list
    unsigned* __restrict__ cnt)
{
    __shared__ uint4 Bl[2][256];      // B tile 64x32 f16, 4 swizzled slots/row
    __shared__ float ny_inv[64];
    __shared__ float rowmaxs[512];
    __shared__ float2 lent[LCAP];
    __shared__ unsigned lcnt, gbase;

    const int tid = threadIdx.x;
    const int y0 = blockIdx.x << 6;   // 512 blocks = 64-row y-chunks

    // W staging (waves 0-3 only): 4 threads/row, 8 f32 (32B) each;
    // 4 lanes = 128B contiguous per row.
    const int rB = tid >> 2, q = tid & 3;        // rB < 64 for tid < 256
    const int wiB = (rB << 2) + (q ^ (rB & 3));
    const float* bP = w + (size_t)(y0 + (rB & 63)) * 4096 + (q << 3);
    const int isStager = (tid < 256);

    // 8 waves = 8 x wm; wave tile 64M x 64N; 32x32x16 f16 frags
    const int lane = tid & 63, wm = tid >> 6;
    const int kh = lane >> 5, cc = lane & 3;
    const uint4* aP = xf16 + (wm << 8) + lane;

    const int rb0 = ((lane & 31)      ) << 2;
    const int rb1 = ((lane & 31) + 32) << 2;
    const int s0 = kh ^ cc, s1 = (2 | kh) ^ cc;

    f32x16 am0n0 = (f32x16)0.f, am0n1 = (f32x16)0.f;
    f32x16 am1n0 = (f32x16)0.f, am1n1 = (f32x16)0.f;

    half8 pa00, pa01, pa10, pa11;     // A set (mi,ks) - SINGLE set (VGPR cap)
    half8 g00, g01, g10, g11;         // B frags (ni,ks)
    f32x4 SAa, SAb;                   // W set A (even tiles) - nt-loaded
    f32x4 SBa, SBb;                   // W set B (odd tiles)
    float nyacc = 0.f;

#define MF(a, b, c) __builtin_amdgcn_mfma_f32_32x32x16_f16(a, b, c, 0, 0, 0)
#define LG0 asm volatile("s_waitcnt lgkmcnt(0)" ::: "memory")
#define SBR __builtin_amdgcn_sched_barrier(0)

#define LOADA(S, tt) { const uint4* p_ = aP + ((size_t)(tt) << 11); \
    S##00 = *(const half8*)(p_);        S##01 = *(const half8*)(p_ + 64); \
    S##10 = *(const half8*)(p_ + 128);  S##11 = *(const half8*)(p_ + 192); }

// NON-TEMPORAL: W is stream-once; nt keeps xf16 resident in L2.
#define LOADW(S, tt) { const f32x4* p_ = (const f32x4*)(bP + ((tt) << 5)); \
    S##a = __builtin_nontemporal_load(p_); \
    S##b = __builtin_nontemporal_load(p_ + 1); }

#define STOREB(buf, S) { uint4 u_; \
    u_.x = pk2h(S##a.x, S##a.y); u_.y = pk2h(S##a.z, S##a.w); \
    u_.z = pk2h(S##b.x, S##b.y); u_.w = pk2h(S##b.z, S##b.w); \
    Bl[buf][wiB] = u_; \
    nyacc = fmaf(S##a.x, S##a.x, nyacc); nyacc = fmaf(S##a.y, S##a.y, nyacc); \
    nyacc = fmaf(S##a.z, S##a.z, nyacc); nyacc = fmaf(S##a.w, S##a.w, nyacc); \
    nyacc = fmaf(S##b.x, S##b.x, nyacc); nyacc = fmaf(S##b.y, S##b.y, nyacc); \
    nyacc = fmaf(S##b.z, S##b.z, nyacc); nyacc = fmaf(S##b.w, S##b.w, nyacc); }

#define LDB(cur) { \
    g00 = *(const half8*)&Bl[cur][rb0 + s0]; g01 = *(const half8*)&Bl[cur][rb0 + s1]; \
    g10 = *(const half8*)&Bl[cur][rb1 + s0]; g11 = *(const half8*)&Bl[cur][rb1 + s1]; }

#define MFMA8 { \
    am0n0 = MF(pa00, g00, am0n0); am0n1 = MF(pa00, g10, am0n1); \
    am1n0 = MF(pa10, g00, am1n0); am1n1 = MF(pa10, g10, am1n1); \
    am0n0 = MF(pa01, g01, am0n0); am0n1 = MF(pa01, g11, am0n1); \
    am1n0 = MF(pa11, g01, am1n0); am1n1 = MF(pa11, g11, am1n1); }

// One K-tile, ONE raw barrier. Single A-set: A(t+1) load issued AFTER this
// tile's MFMAs (register dep); latency hidden by the co-resident block.
#define TILE(cur, tt, WS, GA, GW) { \
    LDB(cur); \
    if (GA && isStager) STOREB((cur) ^ 1, WS); \
    if (GW && isStager) LOADW(WS, (tt) + 3); \
    MFMA8; \
    if (GA) LOADA(pa, (tt) + 1); \
    LG0; SBR; \
    __builtin_amdgcn_s_barrier(); }

    // ---- prologue: W(0)->buf0; W(1)->SA, W(2)->SB; A(0)->pa ----
    if (isStager) {
        LOADW(SA, 0);
        STOREB(0, SA);                // compiler waits SA
        LOADW(SA, 1);
        LOADW(SB, 2);
    }
    LOADA(pa, 0);
    LG0; SBR;
    __builtin_amdgcn_s_barrier();

    for (int t = 0; t < 124; t += 2) {
        TILE(0, t,     SA, 1, 1)
        TILE(1, t + 1, SB, 1, 1)
    }
    TILE(0, 124, SA, 1, 1)           // loads W(127)
    TILE(1, 125, SB, 1, 0)
    TILE(0, 126, SA, 1, 0)           // stores W(127)
    TILE(1, 127, SB, 0, 0)

    // ---- fused ||w_y|| (4 threads/row, waves 0-3) ----
    float s_ = nyacc;
    s_ += __shfl_xor(s_, 1);
    s_ += __shfl_xor(s_, 2);
    if (isStager && q == 0) ny_inv[rB] = 1.0f / fmaxf(sqrtf(s_), 1e-12f);
    if (tid == 0) lcnt = 0u;
    __syncthreads();

    // ---- epilogue ----
    // am{mi}n{ni}[v] = S[wm*64+mi*32+(v&3)+8*(v>>2)+4*kh][y0+ni*32+(lane&31)]
    const int yl0 = (lane & 31), yl1 = yl0 + 32;
    const float scl0 = ny_inv[yl0], scl1 = ny_inv[yl1];
    const int act0 = age[y0 + yl0] >= 1, act1 = age[y0 + yl1] >= 1;
    const int yb0 = y0 + yl0, yb1 = y0 + yl1;
    const int rbase = (wm << 6) + (kh << 2);

#define ROWMAX(A0, A1, mi5) \
    _Pragma("unroll") for (int v = 0; v < 16; ++v) { \
        float bv = fmaxf(act0 ? A0[v] * scl0 : 0.f, act1 ? A1[v] * scl1 : 0.f); \
        _Pragma("unroll") for (int off = 1; off < 32; off <<= 1) \
            bv = fmaxf(bv, __shfl_xor(bv, off)); \
        if ((lane & 31) == 0) \
            rowmaxs[rbase + (mi5) + (v & 3) + ((v >> 2) << 3)] = bv; \
    }
    ROWMAX(am0n0, am0n1, 0)
    ROWMAX(am1n0, am1n1, 32)
    __syncthreads();
    cand[(size_t)tid * 512 + blockIdx.x] = rowmaxs[tid];   // 512 rows
    __syncthreads();

#define APP1(ACv, actk, sclk, ybk, r_) { \
    if (actk) { const float sc_ = (ACv) * sclk; \
        if (sc_ >= rowmaxs[r_] - TAU) { \
            const unsigned ix_ = atomicAdd(&lcnt, 1u); \
            if (ix_ < LCAP) lent[ix_] = make_float2(sc_, \
                __uint_as_float(((unsigned)(r_) << 16) | (unsigned)(ybk))); } } }

#define APPEND(A0, A1, mi5) \
    _Pragma("unroll") for (int v = 0; v < 16; ++v) { \
        const int r_ = rbase + (mi5) + (v & 3) + ((v >> 2) << 3); \
        APP1(A0[v], act0, scl0, yb0, r_) \
        APP1(A1[v], act1, scl1, yb1, r_) }
    APPEND(am0n0, am0n1, 0)
    APPEND(am1n0, am1n1, 32)
    __syncthreads();
    if (tid == 0) gbase = atomicAdd(cnt, min(lcnt, LCAP));
    __syncthreads();
    const unsigned nL = min(lcnt, LCAP);
    for (unsigned i = tid; i < nL; i += 512) {
        const unsigned gi = gbase + i;
        if (gi < CAP) ent[gi] = lent[i];
    }
#undef MF
#undef LG0
#undef SBR
#undef LOADA
#undef LOADW
#undef STOREB
#undef LDB
#undef MFMA8
#undef TILE
#undef ROWMAX
#undef APP1
#undef APPEND
}

__global__ __launch_bounds__(256) void reduce_gmax(const float* __restrict__ cand,
                                                   float* __restrict__ gmax) {
    const int b = blockIdx.x, t = threadIdx.x;
    float m = fmaxf(cand[(size_t)b * 512 + t], cand[(size_t)b * 512 + t + 256]);
    #pragma unroll
    for (int off = 32; off; off >>= 1) m = fmaxf(m, __shfl_xor(m, off));
    __shared__ float sm[4];
    if ((t & 63) == 0) sm[t >> 6] = m;
    __syncthreads();
    if (t == 0) gmax[b] = fmaxf(fmaxf(sm[0], sm[1]), fmaxf(sm[2], sm[3]));
}

// exact f32 rescore; ballot-compacted scan, wave-per-survivor dot product
__global__ __launch_bounds__(256) void rescore(
    const float* __restrict__ x, const float* __restrict__ w,
    const float* __restrict__ gmax, const float2* __restrict__ ent,
    const unsigned* __restrict__ cnt, ull* __restrict__ win)
{
    const unsigned n = min(*cnt, CAP);
    const int lane = threadIdx.x & 63;
    const unsigned wid = (blockIdx.x * 256 + threadIdx.x) >> 6;
    const unsigned nwv = (gridDim.x * 256) >> 6;
    for (unsigned base = wid << 6; base < n; base += (nwv << 6)) {
        const unsigned e = base + (unsigned)lane;
        unsigned by = 0u;
        bool ok = false;
        if (e < n) {
            const float2 en = ent[e];
            by = __float_as_uint(en.y);
            ok = en.x >= gmax[by >> 16] - TAU;
        }
        ull m = __ballot(ok);
        while (m) {
            const int s = __ffsll((ull)m) - 1;
            m &= m - 1;
            const unsigned bys = __shfl(by, s);
            const unsigned b = bys >> 16, y = bys & 0xffffu;
            const float4* xr = (const float4*)(x + (size_t)b * 4096);
            const float4* wr = (const float4*)(w + (size_t)y * 4096);
            float sdot = 0.f, nn = 0.f;
            #pragma unroll
            for (int k = 0; k < 16; ++k) {
                const float4 xv = xr[(k << 6) + lane];
                const float4 wv = wr[(k << 6) + lane];
                sdot = fmaf(xv.x, wv.x, sdot); sdot = fmaf(xv.y, wv.y, sdot);
                sdot = fmaf(xv.z, wv.z, sdot); sdot = fmaf(xv.w, wv.w, sdot);
                nn = fmaf(wv.x, wv.x, nn); nn = fmaf(wv.y, wv.y, nn);
                nn = fmaf(wv.z, wv.z, nn); nn = fmaf(wv.w, wv.w, nn);
            }
            #pragma unroll
            for (int off = 32; off; off >>= 1) {
                sdot += __shfl_xor(sdot, off);
                nn   += __shfl_xor(nn, off);
            }
            if (lane == 0) {
                const float sc = sdot / fmaxf(sqrtf(nn), 1e-12f);
                atomicMax(win + b, packkey(sc, y));
            }
        }
    }
}

__global__ __launch_bounds__(256) void gather_out(const float* __restrict__ y2z,
                                                  const float* __restrict__ nz,
                                                  const ull* __restrict__ win,
                                                  float* __restrict__ out) {
    const int g = blockIdx.x * 256 + threadIdx.x;
    if (g >= 512 * 1000) return;
    const int b = g / 1000, z = g - b * 1000;
    const unsigned lo = (unsigned)(win[b] & 0xffffffffull);
    const int yw = (int)(0x7FFFFFFFu - lo);
    out[g] = y2z[(size_t)z * 32768 + yw] / fmaxf(nz[z], 1e-12f);
}

extern "C" void kernel_launch(void* const* d_in, const int* in_sizes, int n_in,
                              void* d_out, int out_size, void* d_ws, size_t ws_size,
                              hipStream_t stream) {
    const float* x     = (const float*)d_in[0];
    const float* x2y_w = (const float*)d_in[2];
    const float* y2z_w = (const float*)d_in[3];
    const int*   y_age = (const int*)d_in[4];
    float* out = (float*)d_out;

    // ws layout (bytes)
    char* p = (char*)d_ws;
    float*    cand = (float*)p;                       // 512*512*4 = 1048576
    float*    nz   = (float*)(p + 1048576);           // 4096
    float*    gmax = (float*)(p + 1052672);           // 2048
    ull*      win  = (ull*)(p + 1054720);             // 4096
    unsigned* cnt  = (unsigned*)(p + 1058816);        // 64
    uint4*    xf16 = (uint4*)(p + 1058880);           // 4 MB
    float2*   ent  = (float2*)(p + 5253184);          // CAP*8

    init_ctrl<<<1, 512, 0, stream>>>(y_age, win, cnt);
    convert_x<<<512, 512, 0, stream>>>(x, xf16);
    row_norms<<<1000, 256, 0, stream>>>(y2z_w, nz, 32768);

    gemm_f16<<<512, 512, 0, stream>>>(x2y_w, xf16, y_age, cand, ent, cnt);
    reduce_gmax<<<512, 256, 0, stream>>>(cand, gmax);
    rescore<<<256, 256, 0, stream>>>(x, x2y_w, gmax, ent, cnt, win);
    gather_out<<<(512 * 1000 + 255) / 256, 256, 0, stream>>>(y2z_w, nz, win, out);
}

// Round 19
// 263.867 us; speedup vs baseline: 1.3343x; 1.1170x over previous
//
#include <hip/hip_runtime.h>
#include <math.h>

// DN test-mode forward, filter+rescore. FINAL (R15 champion, 265.6us).
// gemm: BM=512 (full M) x BN=128, 256 blocks = 1/CU, W read ONCE (512MB, NT
// loads keep xf16 L2-resident). Raw s_barrier + lgkmcnt(0) only (no vmcnt
// drains); W 2-tile-deep reg prefetch; A (xf16, L2) 1-tile-deep; compiler's
// per-use vmcnt waits are the counted waits (T4 for free).

typedef _Float16 half8 __attribute__((ext_vector_type(8)));
typedef __attribute__((ext_vector_type(16))) float f32x16;
typedef float f32x4 __attribute__((ext_vector_type(4)));
typedef unsigned long long ull;

#define TAU 0.006f
#define CAP 1572864u
#define LCAP 1536u

__device__ __forceinline__ unsigned pk2h(float a, float b) {
    union { _Float16 h; unsigned short u; } ca, cb;
    ca.h = (_Float16)a; cb.h = (_Float16)b;   // RNE
    return (unsigned)ca.u | ((unsigned)cb.u << 16);
}

// monotone-float key, smaller y wins ties
__device__ __forceinline__ ull packkey(float v, unsigned y) {
    unsigned m = __float_as_uint(v);
    m = (v >= 0.f) ? (m | 0x80000000u) : ~m;
    return ((ull)m << 32) | (ull)(0x7FFFFFFFu - y);
}

__global__ __launch_bounds__(512) void init_ctrl(const int* __restrict__ age,
                                                 ull* __restrict__ win,
                                                 unsigned* __restrict__ cnt) {
    const int t = threadIdx.x;
    int fi = 0x7fffffff;
    for (int y = t; y < 32768; y += 512)
        if (age[y] < 1) fi = min(fi, y);
    __shared__ int red[512];
    red[t] = fi;
    __syncthreads();
    for (int s = 256; s; s >>= 1) {
        if (t < s) red[t] = min(red[t], red[t + s]);
        __syncthreads();
    }
    const int f = red[0];
    const ull seed = (f < 32768) ? packkey(0.0f, (unsigned)f) : packkey(-1e30f, 0u);
    win[t] = seed;                      // t < 512 = B
    if (t == 0) *cnt = 0u;
}

// x -> f16 fragments: o = (t<<11)|(wm<<8)|(mi<<7)|(ks<<6)|lane
__global__ __launch_bounds__(512) void convert_x(const float* __restrict__ x,
                                                 uint4* __restrict__ xf16) {
    const int o = blockIdx.x * 512 + threadIdx.x;   // 262144
    const int lane = o & 63;
    const int ks = (o >> 6) & 1;
    const int mi = (o >> 7) & 1;
    const int wm = (o >> 8) & 7;
    const int t  = o >> 11;
    const int row = (wm << 6) + (mi << 5) + (lane & 31);
    const int col = (t << 5) + (ks << 4) + ((lane >> 5) << 3);
    const float* src = x + (size_t)row * 4096 + col;
    const float4 a = *(const float4*)src;
    const float4 b = *(const float4*)(src + 4);
    uint4 u;
    u.x = pk2h(a.x, a.y); u.y = pk2h(a.z, a.w);
    u.z = pk2h(b.x, b.y); u.w = pk2h(b.z, b.w);
    xf16[o] = u;
}

__global__ __launch_bounds__(256) void row_norms(const float* __restrict__ src,
                                                 float* __restrict__ dst, int cols) {
    const int r = blockIdx.x;
    const float* row = src + (size_t)r * cols;
    const int t = threadIdx.x;
    float s = 0.f;
    const int nIter = cols >> 10;
    for (int i = 0; i < nIter; ++i) {
        const float4 v = *reinterpret_cast<const float4*>(row + (((i << 8) + t) << 2));
        s = fmaf(v.x, v.x, s); s = fmaf(v.y, v.y, s);
        s = fmaf(v.z, v.z, s); s = fmaf(v.w, v.w, s);
    }
    #pragma unroll
    for (int off = 32; off; off >>= 1) s += __shfl_down(s, off);
    __shared__ float red[4];
    if ((t & 63) == 0) red[t >> 6] = s;
    __syncthreads();
    if (t == 0) dst[r] = sqrtf(red[0] + red[1] + red[2] + red[3]);
}

__global__ __launch_bounds__(512, 2) void gemm_f16(
    const float* __restrict__ w,      // [32768][4096]
    const uint4* __restrict__ xf16,   // pre-converted x fragments
    const int*  __restrict__ age,
    float* __restrict__ cand,         // [512][256] block-row approx max
    float2* __restrict__ ent,         // candidate list
    unsigned* __restrict__ cnt)
{
    __shared__ uint4 Bl[2][512];      // B tile 128x32 f16, 4 swizzled slots/row
    __shared__ float ny_inv[128];
    __shared__ float rowmaxs[512];
    __shared__ float2 lent[LCAP];
    __shared__ unsigned lcnt, gbase;

    const int tid = threadIdx.x;
    const int y0 = blockIdx.x << 7;   // 256 blocks = y-chunks

    // W staging: 4 threads/row, 8 f32 (32B) each; 4 lanes = 128B contiguous
    const int rB = tid >> 2, q = tid & 3;
    const int wiB = (rB << 2) + (q ^ (rB & 3));
    const float* bP = w + (size_t)(y0 + rB) * 4096 + (q << 3);

    // 8 waves = 8 x wm; wave tile 64M x 128N; 32x32x16 f16 frags
    const int lane = tid & 63, wm = tid >> 6;
    const int kh = lane >> 5, cc = lane & 3;
    const uint4* aP = xf16 + (wm << 8) + lane;

    const int rb0 = ((lane & 31)      ) << 2;
    const int rb1 = ((lane & 31) +  32) << 2;
    const int rb2 = ((lane & 31) +  64) << 2;
    const int rb3 = ((lane & 31) +  96) << 2;
    const int s0 = kh ^ cc, s1 = (2 | kh) ^ cc;

    f32x16 am0n0 = (f32x16)0.f, am0n1 = (f32x16)0.f;
    f32x16 am0n2 = (f32x16)0.f, am0n3 = (f32x16)0.f;
    f32x16 am1n0 = (f32x16)0.f, am1n1 = (f32x16)0.f;
    f32x16 am1n2 = (f32x16)0.f, am1n3 = (f32x16)0.f;

    half8 pa00, pa01, pa10, pa11;     // A set P (mi,ks)
    half8 qa00, qa01, qa10, qa11;     // A set Q
    half8 g00, g10, g20, g30;         // B frags ks0 (ni 0..3)
    half8 g01, g11, g21, g31;         // B frags ks1
    f32x4 SAa, SAb;                   // W set A (even tiles) - nt-loaded
    f32x4 SBa, SBb;                   // W set B (odd tiles)
    float nyacc = 0.f;

#define MF(a, b, c) __builtin_amdgcn_mfma_f32_32x32x16_f16(a, b, c, 0, 0, 0)
#define LG0 asm volatile("s_waitcnt lgkmcnt(0)" ::: "memory")
#define SBR __builtin_amdgcn_sched_barrier(0)

#define LOADA(S, tt) { const uint4* p_ = aP + ((size_t)(tt) << 11); \
    S##00 = *(const half8*)(p_);        S##01 = *(const half8*)(p_ + 64); \
    S##10 = *(const half8*)(p_ + 128);  S##11 = *(const half8*)(p_ + 192); }

// NON-TEMPORAL: W is stream-once; nt keeps xf16 resident in L2.
#define LOADW(S, tt) { const f32x4* p_ = (const f32x4*)(bP + ((tt) << 5)); \
    S##a = __builtin_nontemporal_load(p_); \
    S##b = __builtin_nontemporal_load(p_ + 1); }

#define STOREB(buf, S) { uint4 u_; \
    u_.x = pk2h(S##a.x, S##a.y); u_.y = pk2h(S##a.z, S##a.w); \
    u_.z = pk2h(S##b.x, S##b.y); u_.w = pk2h(S##b.z, S##b.w); \
    Bl[buf][wiB] = u_; \
    nyacc = fmaf(S##a.x, S##a.x, nyacc); nyacc = fmaf(S##a.y, S##a.y, nyacc); \
    nyacc = fmaf(S##a.z, S##a.z, nyacc); nyacc = fmaf(S##a.w, S##a.w, nyacc); \
    nyacc = fmaf(S##b.x, S##b.x, nyacc); nyacc = fmaf(S##b.y, S##b.y, nyacc); \
    nyacc = fmaf(S##b.z, S##b.z, nyacc); nyacc = fmaf(S##b.w, S##b.w, nyacc); }

#define LDB(cur) { \
    g00 = *(const half8*)&Bl[cur][rb0 + s0]; g01 = *(const half8*)&Bl[cur][rb0 + s1]; \
    g10 = *(const half8*)&Bl[cur][rb1 + s0]; g11 = *(const half8*)&Bl[cur][rb1 + s1]; \
    g20 = *(const half8*)&Bl[cur][rb2 + s0]; g21 = *(const half8*)&Bl[cur][rb2 + s1]; \
    g30 = *(const half8*)&Bl[cur][rb3 + s0]; g31 = *(const half8*)&Bl[cur][rb3 + s1]; }

#define MFMA16(S) { \
    am0n0 = MF(S##00, g00, am0n0); am0n1 = MF(S##00, g10, am0n1); \
    am0n2 = MF(S##00, g20, am0n2); am0n3 = MF(S##00, g30, am0n3); \
    am1n0 = MF(S##10, g00, am1n0); am1n1 = MF(S##10, g10, am1n1); \
    am1n2 = MF(S##10, g20, am1n2); am1n3 = MF(S##10, g30, am1n3); \
    am0n0 = MF(S##01, g01, am0n0); am0n1 = MF(S##01, g11, am0n1); \
    am0n2 = MF(S##01, g21, am0n2); am0n3 = MF(S##01, g31, am0n3); \
    am1n0 = MF(S##11, g01, am1n0); am1n1 = MF(S##11, g11, am1n1); \
    am1n2 = MF(S##11, g21, am1n2); am1n3 = MF(S##11, g31, am1n3); }

// One K-tile, ONE raw barrier. No vmcnt anywhere: compiler waits per-use
// (W set consumed 2 tiles after issue; A set 1 tile after issue).
#define TILE(cur, tt, AC, AN, WS, GA, GW) { \
    LDB(cur); \
    if (GA) LOADA(AN, (tt) + 1); \
    if (GA) STOREB((cur) ^ 1, WS); \
    if (GW) LOADW(WS, (tt) + 3); \
    MFMA16(AC); \
    LG0; SBR; \
    __builtin_amdgcn_s_barrier(); }

    // ---- prologue: W(0)->buf0; W(1)->SA, W(2)->SB; A(0)->pa ----
    LOADW(SA, 0);
    LOADA(pa, 0);
    STOREB(0, SA);                    // compiler waits SA
    LOADW(SA, 1);
    LOADW(SB, 2);
    LG0; SBR;
    __builtin_amdgcn_s_barrier();

    for (int t = 0; t < 124; t += 2) {
        TILE(0, t,     pa, qa, SA, 1, 1)
        TILE(1, t + 1, qa, pa, SB, 1, 1)
    }
    TILE(0, 124, pa, qa, SA, 1, 1)    // loads W(127)
    TILE(1, 125, qa, pa, SB, 1, 0)
    TILE(0, 126, pa, qa, SA, 1, 0)    // stores W(127)
    TILE(1, 127, qa, pa, SB, 0, 0)

    // ---- fused ||w_y|| (4 threads/row) ----
    float s_ = nyacc;
    s_ += __shfl_xor(s_, 1);
    s_ += __shfl_xor(s_, 2);
    if (q == 0) ny_inv[rB] = 1.0f / fmaxf(sqrtf(s_), 1e-12f);
    if (tid == 0) lcnt = 0u;
    __syncthreads();

    // ---- epilogue ----
    // am{mi}n{ni}[v] = S[wm*64+mi*32+(v&3)+8*(v>>2)+4*kh][y0+ni*32+(lane&31)]
    const int yl0 = (lane & 31), yl1 = yl0 + 32, yl2 = yl0 + 64, yl3 = yl0 + 96;
    const float scl0 = ny_inv[yl0], scl1 = ny_inv[yl1];
    const float scl2 = ny_inv[yl2], scl3 = ny_inv[yl3];
    const int act0 = age[y0 + yl0] >= 1, act1 = age[y0 + yl1] >= 1;
    const int act2 = age[y0 + yl2] >= 1, act3 = age[y0 + yl3] >= 1;
    const int yb0 = y0 + yl0, yb1 = y0 + yl1, yb2 = y0 + yl2, yb3 = y0 + yl3;
    const int rbase = (wm << 6) + (kh << 2);

#define ROWMAX(A0, A1, A2, A3, mi5) \
    _Pragma("unroll") for (int v = 0; v < 16; ++v) { \
        float bv = fmaxf( \
            fmaxf(act0 ? A0[v] * scl0 : 0.f, act1 ? A1[v] * scl1 : 0.f), \
            fmaxf(act2 ? A2[v] * scl2 : 0.f, act3 ? A3[v] * scl3 : 0.f)); \
        _Pragma("unroll") for (int off = 1; off < 32; off <<= 1) \
            bv = fmaxf(bv, __shfl_xor(bv, off)); \
        if ((lane & 31) == 0) \
            rowmaxs[rbase + (mi5) + (v & 3) + ((v >> 2) << 3)] = bv; \
    }
    ROWMAX(am0n0, am0n1, am0n2, am0n3, 0)
    ROWMAX(am1n0, am1n1, am1n2, am1n3, 32)
    __syncthreads();
    cand[(size_t)tid * 256 + blockIdx.x] = rowmaxs[tid];   // 512 rows
    __syncthreads();

#define APP1(ACv, actk, sclk, ybk, r_) { \
    if (actk) { const float sc_ = (ACv) * sclk; \
        if (sc_ >= rowmaxs[r_] - TAU) { \
            const unsigned ix_ = atomicAdd(&lcnt, 1u); \
            if (ix_ < LCAP) lent[ix_] = make_float2(sc_, \
                __uint_as_float(((unsigned)(r_) << 16) | (unsigned)(ybk))); } } }

#define APPEND(A0, A1, A2, A3, mi5) \
    _Pragma("unroll") for (int v = 0; v < 16; ++v) { \
        const int r_ = rbase + (mi5) + (v & 3) + ((v >> 2) << 3); \
        APP1(A0[v], act0, scl0, yb0, r_) \
        APP1(A1[v], act1, scl1, yb1, r_) \
        APP1(A2[v], act2, scl2, yb2, r_) \
        APP1(A3[v], act3, scl3, yb3, r_) }
    APPEND(am0n0, am0n1, am0n2, am0n3, 0)
    APPEND(am1n0, am1n1, am1n2, am1n3, 32)
    __syncthreads();
    if (tid == 0) gbase = atomicAdd(cnt, min(lcnt, LCAP));
    __syncthreads();
    const unsigned nL = min(lcnt, LCAP);
    for (unsigned i = tid; i < nL; i += 512) {
        const unsigned gi = gbase + i;
        if (gi < CAP) ent[gi] = lent[i];
    }
#undef MF
#undef LG0
#undef SBR
#undef LOADA
#undef LOADW
#undef STOREB
#undef LDB
#undef MFMA16
#undef TILE
#undef ROWMAX
#undef APP1
#undef APPEND
}

__global__ __launch_bounds__(256) void reduce_gmax(const float* __restrict__ cand,
                                                   float* __restrict__ gmax) {
    const int b = blockIdx.x, t = threadIdx.x;
    float m = cand[(size_t)b * 256 + t];
    #pragma unroll
    for (int off = 32; off; off >>= 1) m = fmaxf(m, __shfl_xor(m, off));
    __shared__ float sm[4];
    if ((t & 63) == 0) sm[t >> 6] = m;
    __syncthreads();
    if (t == 0) gmax[b] = fmaxf(fmaxf(sm[0], sm[1]), fmaxf(sm[2], sm[3]));
}

// exact f32 rescore; ballot-compacted scan, wave-per-survivor dot product
__global__ __launch_bounds__(256) void rescore(
    const float* __restrict__ x, const float* __restrict__ w,
    const float* __restrict__ gmax, const float2* __restrict__ ent,
    const unsigned* __restrict__ cnt, ull* __restrict__ win)
{
    const unsigned n = min(*cnt, CAP);
    const int lane = threadIdx.x & 63;
    const unsigned wid = (blockIdx.x * 256 + threadIdx.x) >> 6;
    const unsigned nwv = (gridDim.x * 256) >> 6;
    for (unsigned base = wid << 6; base < n; base += (nwv << 6)) {
        const unsigned e = base + (unsigned)lane;
        unsigned by = 0u;
        bool ok = false;
        if (e < n) {
            const float2 en = ent[e];
            by = __float_as_uint(en.y);
            ok = en.x >= gmax[by >> 16] - TAU;
        }
        ull m = __ballot(ok);
        while (m) {
            const int s = __ffsll((ull)m) - 1;
            m &= m - 1;
            const unsigned bys = __shfl(by, s);
            const unsigned b = bys >> 16, y = bys & 0xffffu;
            const float4* xr = (const float4*)(x + (size_t)b * 4096);
            const float4* wr = (const float4*)(w + (size_t)y * 4096);
            float sdot = 0.f, nn = 0.f;
            #pragma unroll
            for (int k = 0; k < 16; ++k) {
                const float4 xv = xr[(k << 6) + lane];
                const float4 wv = wr[(k << 6) + lane];
                sdot = fmaf(xv.x, wv.x, sdot); sdot = fmaf(xv.y, wv.y, sdot);
                sdot = fmaf(xv.z, wv.z, sdot); sdot = fmaf(xv.w, wv.w, sdot);
                nn = fmaf(wv.x, wv.x, nn); nn = fmaf(wv.y, wv.y, nn);
                nn = fmaf(wv.z, wv.z, nn); nn = fmaf(wv.w, wv.w, nn);
            }
            #pragma unroll
            for (int off = 32; off; off >>= 1) {
                sdot += __shfl_xor(sdot, off);
                nn   += __shfl_xor(nn, off);
            }
            if (lane == 0) {
                const float sc = sdot / fmaxf(sqrtf(nn), 1e-12f);
                atomicMax(win + b, packkey(sc, y));
            }
        }
    }
}

__global__ __launch_bounds__(256) void gather_out(const float* __restrict__ y2z,
                                                  const float* __restrict__ nz,
                                                  const ull* __restrict__ win,
                                                  float* __restrict__ out) {
    const int g = blockIdx.x * 256 + threadIdx.x;
    if (g >= 512 * 1000) return;
    const int b = g / 1000, z = g - b * 1000;
    const unsigned lo = (unsigned)(win[b] & 0xffffffffull);
    const int yw = (int)(0x7FFFFFFFu - lo);
    out[g] = y2z[(size_t)z * 32768 + yw] / fmaxf(nz[z], 1e-12f);
}

extern "C" void kernel_launch(void* const* d_in, const int* in_sizes, int n_in,
                              void* d_out, int out_size, void* d_ws, size_t ws_size,
                              hipStream_t stream) {
    const float* x     = (const float*)d_in[0];
    const float* x2y_w = (const float*)d_in[2];
    const float* y2z_w = (const float*)d_in[3];
    const int*   y_age = (const int*)d_in[4];
    float* out = (float*)d_out;

    // ws layout (bytes)
    char* p = (char*)d_ws;
    float*    cand = (float*)p;                       // 512*256*4 = 524288
    float*    nz   = (float*)(p + 524288);            // 4096
    float*    gmax = (float*)(p + 528384);            // 2048
    ull*      win  = (ull*)(p + 530432);              // 4096
    unsigned* cnt  = (unsigned*)(p + 534528);         // 64
    uint4*    xf16 = (uint4*)(p + 534592);            // 4 MB
    float2*   ent  = (float2*)(p + 4728896);          // CAP*8

    init_ctrl<<<1, 512, 0, stream>>>(y_age, win, cnt);
    convert_x<<<512, 512, 0, stream>>>(x, xf16);
    row_norms<<<1000, 256, 0, stream>>>(y2z_w, nz, 32768);

    gemm_f16<<<256, 512, 0, stream>>>(x2y_w, xf16, y_age, cand, ent, cnt);
    reduce_gmax<<<512, 256, 0, stream>>>(cand, gmax);
    rescore<<<256, 256, 0, stream>>>(x, x2y_w, gmax, ent, cnt, win);
    gather_out<<<(512 * 1000 + 255) / 256, 256, 0, stream>>>(y2z_w, nz, win, out);
}